// Round 11
// baseline (349.190 us; speedup 1.0000x reference)
//
#include <hip/hip_runtime.h>
#include <math.h>

#define NPG 75
#define KDIM 5

typedef _Float16 half8 __attribute__((ext_vector_type(8)));
typedef float f32x4 __attribute__((ext_vector_type(4)));

__device__ __forceinline__ float eluf(float v){ return v > 0.f ? v : expf(v) - 1.f; }

__device__ __forceinline__ void atomAddF(float* p, float v){ unsafeAtomicAdd(p, v); }

__device__ __forceinline__ unsigned fenc(float f){
    unsigned u = __float_as_uint(f);
    return (u & 0x80000000u) ? ~u : (u | 0x80000000u);
}
__device__ __forceinline__ float fdec(unsigned u){
    return (u & 0x80000000u) ? __uint_as_float(u & 0x7FFFFFFFu) : __uint_as_float(~u);
}

// 25 accumulating FMAs with accumulators pinned to arch VGPRs ("v" constraint).
__device__ __forceinline__ void fma25(float (&r)[25], const float (&wx)[5], const float (&wyx)[5]){
    #pragma unroll
    for (int b1 = 0; b1 < 5; b1++)
        #pragma unroll
        for (int b0 = 0; b0 < 5; b0++)
            asm("v_fmac_f32 %0, %1, %2" : "+v"(r[b1 * 5 + b0]) : "v"(wx[b0]), "v"(wyx[b1]));
}

// spline basis: pseudo = cart/(2*amax)+0.5, clip[0,1], *4; 4 corner weights + kernel ids
__device__ __forceinline__ void spline2(float c0, float c1, float am, int* kks, float* wsp){
    float denom = 2.f * fmaxf(am, 1e-12f);
    float p0 = c0 / denom + 0.5f;
    float p1 = c1 / denom + 0.5f;
    p0 = fminf(fmaxf(p0, 0.f), 1.f) * 4.f;
    p1 = fminf(fmaxf(p1, 0.f), 1.f) * 4.f;
    float b0 = fminf(floorf(p0), 3.f);
    float b1 = fminf(floorf(p1), 3.f);
    float f0 = p0 - b0, f1 = p1 - b1;
    int i0 = (int)b0, i1 = (int)b1;
    wsp[0] = (1.f - f0) * (1.f - f1); kks[0] = i0     + KDIM *  i1;
    wsp[1] =        f0  * (1.f - f1); kks[1] = i0 + 1 + KDIM *  i1;
    wsp[2] = (1.f - f0) *        f1 ; kks[2] = i0     + KDIM * (i1 + 1);
    wsp[3] =        f0  *        f1 ; kks[3] = i0 + 1 + KDIM * (i1 + 1);
}

// per-lane spline payload write (identical arithmetic to the old espline_k)
__device__ __forceinline__ void spline_pay(float2 c, float denom, float* d){
    float p0 = fminf(fmaxf(c.x / denom + 0.5f, 0.f), 1.f) * 4.f;
    float p1 = fminf(fmaxf(c.y / denom + 0.5f, 0.f), 1.f) * 4.f;
    float b0 = fminf(floorf(p0), 3.f);
    float b1 = fminf(floorf(p1), 3.f);
    int i0 = (int)b0, i1 = (int)b1;
    float f0 = p0 - b0, f1 = p1 - b1;
    #pragma unroll
    for (int k = 0; k < 4; k++){
        d[k]     = (k == i0) ? (1.f - f0) : ((k == i0 + 1) ? f0 : 0.f);
        d[4 + k] = (k == i1) ? (1.f - f1) : ((k == i1 + 1) ? f1 : 0.f);
    }
}

// ---------------- prep: W-swizzle (blocks [0,nW)) + edge amax (blocks [nW,nW+gA)) in ONE dispatch ----------------
__global__ __launch_bounds__(256) void prep_k(
        const float* __restrict__ W2, const float* __restrict__ r2,
        const float* __restrict__ W3, const float* __restrict__ r3,
        _Float16* __restrict__ Wz2, _Float16* __restrict__ Wz3, int nW,
        const float* __restrict__ pos, const int* __restrict__ src,
        const int* __restrict__ dst, int E4, int gA, unsigned* __restrict__ outbits){
    const int blk = blockIdx.x;
    if (blk < nW){
        int gid = blk * 256 + threadIdx.x;
        const int T2 = 26 * 32 * 64;
        const int T3 = 26 * 64 * 64;
        const float* W; const float* root; _Float16* Wz; int FIN; int g;
        if (gid < T2){ W = W2; root = r2; Wz = Wz2; FIN = 32; g = gid; }
        else if (gid < T2 + T3){ W = W3; root = r3; Wz = Wz3; FIN = 64; g = gid - T2; }
        else return;
        int k = g >> 6, n = g & 63;
        float v = (k < 25 * FIN) ? W[(size_t)k * 64 + n] : root[(size_t)(k - 25 * FIN) * 64 + n];
        int kt = k >> 5, kr = k & 31, quad = kr >> 3, j = kr & 7;
        int lane = (quad << 4) | (n & 15);
        int nt = n >> 4;
        Wz[(((size_t)(kt * 4 + nt) * 64 + lane) << 3) + j] = (_Float16)v;
    } else {
        float cand = 0.f;
        for (int i = (blk - nW) * 256 + threadIdx.x; i < E4; i += gA * 256){
            int4 s4 = ((const int4*)src)[i];
            int4 d4 = ((const int4*)dst)[i];
            #pragma unroll
            for (int k = 0; k < 4; k++){
                int s = (&s4.x)[k], d = (&d4.x)[k];
                float c0 = pos[s*2]   - pos[d*2];
                float c1 = pos[s*2+1] - pos[d*2+1];
                cand = fmaxf(cand, fmaxf(fabsf(c0), fabsf(c1)));
            }
        }
        __shared__ float sm[256];
        sm[threadIdx.x] = cand; __syncthreads();
        for (int o = 128; o > 0; o >>= 1){
            if (threadIdx.x < o) sm[threadIdx.x] = fmaxf(sm[threadIdx.x], sm[threadIdx.x + o]);
            __syncthreads();
        }
        if (threadIdx.x == 0) atomicMax(outbits, __float_as_uint(sm[0]));
    }
}

// ---------------- conv1 (Fin=1->32) + pool1 + stage1->2 dedup/CSR, fully fused, 1 block/graph ----------------
__global__ __launch_bounds__(512) void conv1dedup_k(
        const float* __restrict__ x, const float* __restrict__ pos,
        const int* __restrict__ src, const int* __restrict__ dst, int EPG,
        const unsigned* __restrict__ amaxp,
        const float* __restrict__ W1, const float* __restrict__ r1, const float* __restrict__ b1,
        float* __restrict__ px1, float* __restrict__ pp1, float* __restrict__ sv1,
        int* __restrict__ easrc, float2* __restrict__ ecart,
        int* __restrict__ rowptr2, int* __restrict__ kcnt, unsigned* __restrict__ amaxbits){
    __shared__ __align__(16) float acc[NPG * 28];
    __shared__ float deg[NPG];
    __shared__ float xl[NPG], p0l[NPG], p1l[NPG];
    __shared__ int   cli[NPG];
    __shared__ float W1s[800], r1s[32], b1s[32];
    __shared__ unsigned px[36 * 32];
    __shared__ float cnt[36], ps[72], ppS[72];
    __shared__ unsigned pm[36 * 36];
    __shared__ float degs[36];
    __shared__ int rs[37], cur[36];
    __shared__ float red[8];
    __shared__ unsigned short sdS[2048];   // packed (s | d<<8) per edge

    const int b = blockIdx.x, t = threadIdx.x;
    const int lane = t & 63, wid = t >> 6;
    const int n0 = b * NPG, e0 = b * EPG;

    const float am = __uint_as_float(*amaxp);

    for (int i = t; i < NPG * 28; i += 512) acc[i] = 0.f;
    for (int i = t; i < 36 * 32; i += 512) px[i] = 0u;
    for (int i = t; i < 36 * 36; i += 512) pm[i] = 0xFFFFFFFFu;
    if (t < NPG) deg[t] = 0.f;
    if (t < 36){ cnt[t] = 0.f; degs[t] = 0.f; }
    if (t < 72) ps[t] = 0.f;
    for (int i = t; i < 800; i += 512) W1s[i] = W1[i];
    if (t < 32){ r1s[t] = r1[t]; b1s[t] = b1[t]; }
    if (t < NPG){
        float p0 = pos[(n0 + t) * 2], p1 = pos[(n0 + t) * 2 + 1];
        xl[t] = x[n0 + t]; p0l[t] = p0; p1l[t] = p1;
        int c0 = min(max((int)floorf(p0 / 5.f), 0), 5);
        int c1 = min(max((int)floorf(p1 / 5.f), 0), 5);
        cli[t] = c1 * 6 + c0;
    }
    __syncthreads();   // B1

    if (t < NPG){
        int c = cli[t];
        atomAddF(&cnt[c], 1.f);
        atomAddF(&ps[c*2],     p0l[t]);
        atomAddF(&ps[c*2 + 1], p1l[t]);
    }
    #pragma unroll 4
    for (int it = 0; it < 4; it++){
        int e = t + it * 512;
        if (e < EPG){
            int s = src[e0 + e] - n0;
            int d = dst[e0 + e] - n0;
            sdS[e] = (unsigned short)(s | (d << 8));
            float c0 = p0l[s] - p0l[d];
            float c1 = p1l[s] - p1l[d];
            int kks[4]; float wsp[4];
            spline2(c0, c1, am, kks, wsp);
            float xv = xl[s];
            #pragma unroll
            for (int c = 0; c < 4; c++) atomAddF(&acc[d*28 + kks[c]], wsp[c] * xv);
            atomAddF(&deg[d], 1.f);
        }
    }
    __syncthreads();   // B2

    if (t < 36){
        float c = cnt[t], m = fmaxf(c, 1.f);
        float q0 = ps[t*2] / m, q1 = ps[t*2 + 1] / m;
        ppS[t*2] = q0; ppS[t*2 + 1] = q1;
        pp1[(b*36 + t)*2]     = q0;
        pp1[(b*36 + t)*2 + 1] = q1;
        sv1[b*36 + t] = (c > 0.f) ? 1.f : 0.f;
    }
    {
        const int o = t & 31;
        float wreg[25];
        #pragma unroll
        for (int k = 0; k < 25; k++) wreg[k] = W1s[k * 32 + o];
        const float rro = r1s[o], bbo = b1s[o];
        const int ii = t >> 5;
        #pragma unroll
        for (int r = 0; r < 5; r++){
            int i = ii + r * 16;
            if (i < NPG){
                const float4* ar = (const float4*)(acc + i * 28);
                float s = 0.f;
                #pragma unroll
                for (int q = 0; q < 7; q++){
                    float4 aq = ar[q];
                    s += aq.x * wreg[q*4];
                    if (q*4 + 1 < 25) s += aq.y * wreg[q*4 + 1];
                    if (q*4 + 2 < 25) s += aq.z * wreg[q*4 + 2];
                    if (q*4 + 3 < 25) s += aq.w * wreg[q*4 + 3];
                }
                float v = s / fmaxf(deg[i], 1.f) + xl[i] * rro + bbo;
                v = eluf(v);
                atomicMax(&px[cli[i]*32 + o], fenc(v));
            }
        }
    }
    int lab[4];
    #pragma unroll 4
    for (int it = 0; it < 4; it++){
        int e = t + it * 512;
        lab[it] = 0;
        if (e < EPG){
            int sd = (int)sdS[e];
            int a  = cli[sd & 255];
            int bb = cli[sd >> 8];
            lab[it] = a | (bb << 8) | ((a != bb) ? 0x10000 : 0);
            if (a != bb) atomicMin(&pm[a * 36 + bb], (unsigned)e);
        }
    }
    __syncthreads();   // B3

    for (int idx = t; idx < 36 * 32; idx += 512){
        int s_ = idx >> 5;
        px1[(size_t)(b*36)*32 + idx] = (cnt[s_] > 0.f) ? fdec(px[idx]) : 0.f;
    }
    float cand = 0.f;
    unsigned keptM = 0;
    #pragma unroll 4
    for (int it = 0; it < 4; it++){
        int e = t + it * 512;
        int L = lab[it];
        if (L & 0x10000){
            int a = L & 255, bb = (L >> 8) & 255;
            if (pm[a * 36 + bb] == (unsigned)e){
                keptM |= 1u << it;
                atomAddF(&degs[bb], 1.f);
                float c0 = ppS[a*2]     - ppS[bb*2];
                float c1 = ppS[a*2 + 1] - ppS[bb*2 + 1];
                cand = fmaxf(cand, fmaxf(fabsf(c0), fabsf(c1)));
            }
        }
    }
    #pragma unroll
    for (int o = 1; o < 64; o <<= 1) cand = fmaxf(cand, __shfl_xor(cand, o, 64));
    if (lane == 0) red[wid] = cand;
    __syncthreads();   // B4
    if (t == 0){
        float m = red[0];
        #pragma unroll
        for (int i = 1; i < 8; i++) m = fmaxf(m, red[i]);
        atomicMax(amaxbits, __float_as_uint(m));
    }
    if (t < 64){
        int v = (t < 36) ? (int)degs[t] : 0;
        int incl = v;
        #pragma unroll
        for (int o = 1; o < 64; o <<= 1){
            int u = __shfl_up(incl, o, 64);
            if (t >= o) incl += u;
        }
        if (t == 0) rs[0] = 0;
        if (t < 36) rs[t + 1] = incl;
    }
    __syncthreads();   // B5
    if (t < 36){
        rowptr2[(b*36 + t)*2]     = e0 + rs[t];
        rowptr2[(b*36 + t)*2 + 1] = e0 + rs[t + 1];
        cur[t] = rs[t];
    }
    if (t == 0) kcnt[b] = rs[36];
    __syncthreads();   // B6
    #pragma unroll 4
    for (int it = 0; it < 4; it++){
        if (keptM & (1u << it)){
            int L = lab[it];
            int a = L & 255, bb = (L >> 8) & 255;
            int slot = atomicAdd(&cur[bb], 1);
            easrc[e0 + slot] = b*36 + a;
            ecart[e0 + slot] = make_float2(ppS[a*2] - ppS[bb*2], ppS[a*2 + 1] - ppS[bb*2 + 1]);
        }
    }
}

// ---------------- conv2 phase A: gather with wave-parallel inline spline (round-6 verified) ----------------
__global__ __launch_bounds__(256) void conv_gather32_k(
        const float* __restrict__ x, const int* __restrict__ easrc,
        const float2* __restrict__ ecart, const unsigned* __restrict__ amaxp,
        const int* __restrict__ rowptr2, _Float16* __restrict__ Aout){
    constexpr int FIN = 32;
    constexpr int KTOT = 26 * FIN;
    __shared__ __align__(16) float pay[4][36][8];
    __shared__ int asrcS[4][36];
    const int w = threadIdx.x >> 6, lane = threadIdx.x & 63;
    const int node = blockIdx.x * 4 + w;
    const int row0 = rowptr2[node*2], row1 = rowptr2[node*2 + 1];
    const int ne = row1 - row0;
    const int sub = lane >> 5;
    const int f = lane & (FIN - 1);

    if (lane < ne){
        float am = __uint_as_float(*amaxp);
        spline_pay(ecart[row0 + lane], 2.f * fmaxf(am, 1e-12f), &pay[w][lane][0]);
        asrcS[w][lane] = easrc[row0 + lane];
    }
    // wave-coherent LDS: no barrier needed

    float r[25];
    #pragma unroll
    for (int b = 0; b < 25; b++) r[b] = 0.f;

    int j = sub;
    int aNext = 0;
    float xvCur = 0.f;
    if (j < ne){
        int aCur = asrcS[w][j];
        xvCur = x[(size_t)aCur * FIN + f];
        int j1 = (j + 2 < ne) ? j + 2 : j;
        aNext = asrcS[w][j1];
    }
    for (; j < ne; j += 2){
        int jN  = j + 2;
        int jNs = (jN < ne) ? jN : j;
        int jN2 = (jN + 2 < ne) ? jN + 2 : jNs;
        float xvN = x[(size_t)aNext * FIN + f];   // aNext resolved last iteration
        int aN2 = asrcS[w][jN2];
        float4 wa = *(const float4*)&pay[w][j][0];
        float4 wb = *(const float4*)&pay[w][j][4];
        float wx4 = 1.f - (wa.x + wa.y + wa.z + wa.w);
        float wy4 = 1.f - (wb.x + wb.y + wb.z + wb.w);
        float wx[5]  = {wa.x, wa.y, wa.z, wa.w, wx4};
        float wyx[5] = {wb.x * xvCur, wb.y * xvCur, wb.z * xvCur, wb.w * xvCur, wy4 * xvCur};
        fma25(r, wx, wyx);
        xvCur = xvN; aNext = aN2;
    }

    #pragma unroll
    for (int b = 0; b < 25; b++) r[b] += __shfl_xor(r[b], 32, 64);

    float inv = 1.f / (float)max(ne, 1);
    _Float16* dstrow = Aout + (size_t)node * KTOT;
    #pragma unroll
    for (int b = 0; b < 25; b++)
        if ((b & 1) == sub) dstrow[b * 32 + f] = (_Float16)(r[b] * inv);
    if (sub == 0) dstrow[25 * 32 + f] = (_Float16)x[(size_t)node * 32 + f];
}

// ---------------- conv2 phase B FUSED with pool2 + stage2->3 dedup/CSR, one block (256 thr) per graph ----------------
// MFMA M=48 (36 valid rows, zero-fragment guard) x N=64 x K=832; out2 NEVER materializes:
// the MFMA epilogue pools eluf(acc+bias) directly into the LDS px-max. Dedup logic is
// dedup_pool_k verbatim (loops re-indexed 1024 -> 256 threads).
__global__ __launch_bounds__(256) void mfma2pool_k(
        const _Float16* __restrict__ A, const _Float16* __restrict__ Wz,
        const float* __restrict__ bias,
        const int* __restrict__ easrc_in, const int* __restrict__ rowptr_in,
        const int* __restrict__ kcnt_in,
        const float* __restrict__ pp1, const float* __restrict__ sv1,
        int EPG,
        float* __restrict__ px2, float* __restrict__ pp2, float* __restrict__ sv2,
        int* __restrict__ easrc, float2* __restrict__ ecart,
        int* __restrict__ rowptr3, int* __restrict__ kcnt, unsigned* __restrict__ amaxbits){
    constexpr int GG = 25, NN = 36;
    __shared__ unsigned pm[GG * GG];
    __shared__ float degs[GG];
    __shared__ int rs[GG + 1];
    __shared__ int cur[GG];
    __shared__ float red[4];
    __shared__ int   clS[NN];
    __shared__ int   vld[NN];
    __shared__ int   rsS[NN + 1];
    __shared__ float ppS[2 * GG];
    __shared__ unsigned px[GG * 64];
    __shared__ float cnt[GG], ps[2 * GG];
    __shared__ unsigned short abS[1280];   // packed (a2 | b2<<8 | valid<<15) per kept slot

    const int b = blockIdx.x, t = threadIdx.x;
    const int w = t >> 6, lane = t & 63;
    const int e0 = b * EPG;
    const int cb25 = b * GG;
    const int nb36 = b * NN;

    for (int i = t; i < GG * GG; i += 256) pm[i] = 0xFFFFFFFFu;
    for (int i = t; i < GG * 64; i += 256) px[i] = 0u;
    if (t < GG){ degs[t] = 0.f; cnt[t] = 0.f; }
    if (t < 2 * GG) ps[t] = 0.f;
    if (t < NN){
        float v  = sv1[nb36 + t];
        float p0 = pp1[(nb36 + t)*2], p1 = pp1[(nb36 + t)*2 + 1];
        int c0 = min(max((int)floorf(p0 / 7.f), 0), 4);
        int c1 = min(max((int)floorf(p1 / 7.f), 0), 4);
        clS[t] = c1 * 5 + c0;
        vld[t] = (v > 0.f) ? 1 : 0;
        rsS[t] = rowptr_in[(nb36 + t)*2] - e0;
    }
    if (t == 0) rsS[NN] = kcnt_in[b];
    __syncthreads();   // B1

    const int kn = rsS[NN];

    // pos pooling (sums over valid stage-2 nodes)
    if (t < NN && vld[t]){
        int c = clS[t];
        atomAddF(&cnt[c], 1.f);
        atomAddF(&ps[c*2],     pp1[(nb36 + t)*2]);
        atomAddF(&ps[c*2 + 1], pp1[(nb36 + t)*2 + 1]);
    }
    // pass 0: map kept stage-2 slots to stage-3 cluster pairs; first-slot marking (dedup_pool verbatim)
    #pragma unroll 6
    for (int it = 0; it < 6; it++){
        int s = t + it * 256;
        if (s < kn){
            int r = 0;
            while (r < NN - 1 && rsS[r + 1] <= s) r++;   // dst row of this slot
            int a2 = clS[easrc_in[e0 + s] - nb36];
            int b2 = clS[r];
            abS[s] = (unsigned short)(a2 | (b2 << 8) | ((a2 != b2) ? 0x8000 : 0));
            if (a2 != b2) atomicMin(&pm[a2 * GG + b2], (unsigned)s);
        }
    }
    // MFMA conv2 (conv_mfma832 fragment scheme): 12 tiles (mt 0..2, nt 0..3) over 4 waves;
    // epilogue pools eluf(acc+bias) straight into px (fenc max) — out2 never stored.
    {
        const int quad = lane >> 4, c_ = lane & 15;
        const half8* __restrict__ Wp = (const half8*)Wz + lane;
        #pragma unroll
        for (int tt = 0; tt < 3; tt++){
            const int tile = w + tt * 4;
            const int mt = tile >> 2, nt = tile & 3;
            const int row_l = mt * 16 + c_;             // A-row per lane (col=lane&15 convention)
            const bool rok = (row_l < NN);
            const half8* Arow = rok ? (const half8*)(A + (size_t)(nb36 + row_l) * 832) : (const half8*)A;
            f32x4 acc = (f32x4){0.f, 0.f, 0.f, 0.f};
            for (int kt = 0; kt < 26; kt++){
                half8 a = rok ? Arow[kt * 4 + quad] : (half8){};
                half8 bb = Wp[(kt * 4 + nt) * 64];
                acc = __builtin_amdgcn_mfma_f32_16x16x32_f16(a, bb, acc, 0, 0, 0);
            }
            // C layout: row = mt*16 + quad*4 + i, col = nt*16 + (lane&15)
            const int r_ = quad * 4;
            float bv = bias[nt * 16 + c_];
            #pragma unroll
            for (int i = 0; i < 4; i++){
                int rowp = mt * 16 + r_ + i;
                if (rowp < NN && vld[rowp]){
                    float v = eluf(acc[i] + bv);
                    atomicMax(&px[clS[rowp]*64 + nt * 16 + c_], fenc(v));
                }
            }
        }
    }
    __syncthreads();   // B2 — cnt/ps/px/pm/abS complete

    // pooled outputs: pp2/sv2 (+ ppS for cart), px2 from px
    if (t < GG){
        float c = cnt[t], m = fmaxf(c, 1.f);
        float q0 = ps[t*2] / m, q1 = ps[t*2 + 1] / m;
        ppS[t*2] = q0; ppS[t*2 + 1] = q1;
        pp2[(cb25 + t)*2]     = q0;
        pp2[(cb25 + t)*2 + 1] = q1;
        sv2[cb25 + t] = (c > 0.f) ? 1.f : 0.f;
    }
    for (int idx = t; idx < GG * 64; idx += 256){
        int s_ = idx >> 6;
        px2[(size_t)cb25*64 + idx] = (cnt[s_] > 0.f) ? fdec(px[idx]) : 0.f;
    }
    __syncthreads();   // B3 — ppS ready

    // pass 2: keep + degs + amax candidate (dedup_pool verbatim)
    float cand = 0.f;
    #pragma unroll 6
    for (int it = 0; it < 6; it++){
        int s = t + it * 256;
        if (s < kn){
            int A_ = (int)abS[s];
            if (A_ & 0x8000){
                int a2 = A_ & 255, b2 = (A_ >> 8) & 127;
                if (pm[a2 * GG + b2] == (unsigned)s){
                    atomAddF(&degs[b2], 1.f);
                    float c0 = ppS[a2*2]     - ppS[b2*2];
                    float c1 = ppS[a2*2 + 1] - ppS[b2*2 + 1];
                    cand = fmaxf(cand, fmaxf(fabsf(c0), fabsf(c1)));
                }
            }
        }
    }
    #pragma unroll
    for (int o = 1; o < 64; o <<= 1) cand = fmaxf(cand, __shfl_xor(cand, o, 64));
    if (lane == 0) red[w] = cand;
    __syncthreads();   // B4
    if (t == 0){
        float m = red[0];
        #pragma unroll
        for (int i = 1; i < 4; i++) m = fmaxf(m, red[i]);
        atomicMax(amaxbits, __float_as_uint(m));
    }
    if (t < 64){
        int v = (t < GG) ? (int)degs[t] : 0;
        int incl = v;
        #pragma unroll
        for (int o = 1; o < 64; o <<= 1){
            int u = __shfl_up(incl, o, 64);
            if (t >= o) incl += u;
        }
        if (t == 0) rs[0] = 0;
        if (t < GG) rs[t + 1] = incl;
    }
    __syncthreads();   // B5
    if (t < GG){
        rowptr3[(cb25 + t)*2]     = e0 + rs[t];
        rowptr3[(cb25 + t)*2 + 1] = e0 + rs[t + 1];
        cur[t] = rs[t];
    }
    if (t == 0) kcnt[b] = rs[GG];
    __syncthreads();   // B6
    // pass 3: compaction (easrc/ecart overwritten in place — inputs fully consumed via abS)
    #pragma unroll 6
    for (int it = 0; it < 6; it++){
        int s = t + it * 256;
        if (s < kn){
            int A_ = (int)abS[s];
            if (A_ & 0x8000){
                int a2 = A_ & 255, b2 = (A_ >> 8) & 127;
                if (pm[a2 * GG + b2] == (unsigned)s){
                    int slot = atomicAdd(&cur[b2], 1);
                    easrc[e0 + slot] = cb25 + a2;
                    ecart[e0 + slot] = make_float2(ppS[a2*2] - ppS[b2*2], ppS[a2*2 + 1] - ppS[b2*2 + 1]);
                }
            }
        }
    }
}

// ---------------- conv3pf: per-graph conv3 (gather from global px2 + MFMA K-split) + final pool + MLP ----------------
// (round-10 verified, unchanged)
__global__ __launch_bounds__(1024) void conv3pf_k(
        const float* __restrict__ x,                                     // px2 [S2][64]
        const int* __restrict__ easrc, const float2* __restrict__ ecart,
        const unsigned* __restrict__ amaxp,
        const int* __restrict__ rowptr3,
        const _Float16* __restrict__ Wz, const float* __restrict__ bias,
        const float* __restrict__ pp2, const float* __restrict__ sv2,
        const float* __restrict__ fw1, const float* __restrict__ fb1,
        const float* __restrict__ fw2, const float* __restrict__ fb2,
        float* __restrict__ out){
    constexpr int PAD = 1672;  // 1664 + 8
    __shared__ __align__(16) _Float16 Alds[32 * PAD];     // 107,008 B
    // scr phase A: pay[16][24][8] = [0,3072) ; phase B: Cpart [0,2048) | out3L [2048,4096)
    __shared__ __align__(16) float scr[4096];
    __shared__ int asrcS[16][24];
    __shared__ unsigned px4[4 * 64];
    __shared__ float cnt4[4];
    __shared__ int cli25[25];
    __shared__ float xr[256];
    __shared__ float h[128];
    __shared__ float lg[10];
    __shared__ float lse;

    const int b = blockIdx.x, t = threadIdx.x;
    const int w = t >> 6, lane = t & 63;
    const int cb25 = b * 25;

    // init: zero A-tile rows 25..31; px4/cnt4; final-pool cluster ids from pp2/sv2
    {
        unsigned* az = (unsigned*)&Alds[25 * PAD];
        for (int i = t; i < 7 * PAD / 2; i += 1024) az[i] = 0u;
    }
    if (t < 256) px4[t] = 0u;
    if (t < 4) cnt4[t] = 0.f;
    if (t < 25){
        float v = sv2[cb25 + t];
        float p0 = pp2[(cb25 + t)*2], p1 = pp2[(cb25 + t)*2 + 1];
        int c0 = min(max((int)floorf(p0 / 14.f), 0), 1);
        int c1 = min(max((int)floorf(p1 / 14.f), 0), 1);
        cli25[t] = (v > 0.f) ? (c1 * 2 + c0) : -1;
    }

    // gather (conv3f verbatim; x = px2 global, node = cb25 + nloc, guard nloc < 25)
    const float am = __uint_as_float(*amaxp);
    const float denom = 2.f * fmaxf(am, 1e-12f);
    float* payW = scr + w * 192;

    #pragma unroll
    for (int i = 0; i < 2; i++){
        const int nloc = w * 2 + i;
        if (nloc < 25){
            const int node = cb25 + nloc;
            const int row0 = rowptr3[node*2], row1 = rowptr3[node*2 + 1];
            const int ne = row1 - row0;   // <= 24

            if (lane < ne){
                spline_pay(ecart[row0 + lane], denom, payW + lane * 8);
                asrcS[w][lane] = easrc[row0 + lane];   // global stage-3 cluster id
            }
            // wave-coherent LDS: no barrier needed

            float r[25];
            #pragma unroll
            for (int bq = 0; bq < 25; bq++) r[bq] = 0.f;

            int j = 0;
            int aNext = 0;
            float xvCur = 0.f;
            if (j < ne){
                int aCur = asrcS[w][j];
                xvCur = x[(size_t)aCur * 64 + lane];
                int j1 = (1 < ne) ? 1 : 0;
                aNext = asrcS[w][j1];
            }
            for (; j < ne; j++){
                int jN  = j + 1;
                int jNs = (jN < ne) ? jN : j;
                int jN2 = (jN + 1 < ne) ? jN + 1 : jNs;
                float xvN = x[(size_t)aNext * 64 + lane];
                int aN2 = asrcS[w][jN2];
                float4 wa = *(const float4*)(payW + j * 8);
                float4 wb = *(const float4*)(payW + j * 8 + 4);
                float wx4 = 1.f - (wa.x + wa.y + wa.z + wa.w);
                float wy4 = 1.f - (wb.x + wb.y + wb.z + wb.w);
                float wx[5]  = {wa.x, wa.y, wa.z, wa.w, wx4};
                float wyx[5] = {wb.x * xvCur, wb.y * xvCur, wb.z * xvCur, wb.w * xvCur, wy4 * xvCur};
                fma25(r, wx, wyx);
                xvCur = xvN; aNext = aN2;
            }

            float inv = 1.f / (float)max(ne, 1);
            _Float16* dstrow = &Alds[nloc * PAD];
            #pragma unroll
            for (int bq = 0; bq < 25; bq++) dstrow[bq * 64 + lane] = (_Float16)(r[bq] * inv);
            dstrow[25 * 64 + lane] = (_Float16)x[(size_t)node * 64 + lane];
        }
    }
    __syncthreads();   // BA — gather + zero-fill complete; pay region dead

    if (t < 25 && cli25[t] >= 0) atomAddF(&cnt4[cli25[t]], 1.f);

    float* Cpart = scr;            // [8][256]
    float* out3L = scr + 2048;     // [32][64]

    // MFMA (conv3f verbatim): 8 tiles (mt 0..1, nt 0..3) x K-split 2
    const int tile = w & 7, khalf = w >> 3;
    const int mt = tile >> 2, nt = tile & 3;
    const int quad = lane >> 4, mr = lane & 15;
    f32x4 acc = (f32x4){0.f, 0.f, 0.f, 0.f};
    const _Float16* arow = &Alds[(mt * 16 + mr) * PAD];
    const half8* __restrict__ Wp = (const half8*)Wz + lane;
    const int kt0 = khalf * 26;
    for (int kt = 0; kt < 26; kt++){
        half8 a = *(const half8*)(arow + (kt0 + kt) * 32 + quad * 8);
        half8 bb = Wp[((kt0 + kt) * 4 + nt) * 64];
        acc = __builtin_amdgcn_mfma_f32_16x16x32_f16(a, bb, acc, 0, 0, 0);
    }
    const int r_ = quad * 4, c_ = lane & 15;
    if (khalf == 1){
        float* Cp = Cpart + tile * 256;
        #pragma unroll
        for (int i = 0; i < 4; i++) Cp[(r_ + i) * 16 + c_] = acc[i];
    }
    __syncthreads();   // BB
    if (khalf == 0){
        const float* Cp = Cpart + tile * 256;
        float bv = bias[nt * 16 + c_];
        #pragma unroll
        for (int i = 0; i < 4; i++)
            out3L[(mt * 16 + r_ + i) * 64 + nt * 16 + c_] = eluf(acc[i] + Cp[(r_ + i) * 16 + c_] + bv);
    }
    __syncthreads();   // BC — out3 rows 0..24 valid in LDS

    // final pool (2x2) + MLP + log_softmax (final_k verbatim, xin = out3L)
    for (int idx = t; idx < 25 * 64; idx += 1024){
        int i = idx >> 6, f = idx & 63;
        if (cli25[i] >= 0)
            atomicMax(&px4[cli25[i]*64 + f], fenc(out3L[i * 64 + f]));
    }
    __syncthreads();   // BD
    if (t < 256) xr[t] = (cnt4[t >> 6] > 0.f) ? fdec(px4[t]) : 0.f;
    __syncthreads();   // BE
    if (t < 128){
        float s = fb1[t];
        const float4* wrow = (const float4*)(fw1 + (size_t)t * 256);
        #pragma unroll 4
        for (int i = 0; i < 64; i++){
            float4 q = wrow[i];
            s += xr[i*4]   * q.x;
            s += xr[i*4+1] * q.y;
            s += xr[i*4+2] * q.z;
            s += xr[i*4+3] * q.w;
        }
        h[t] = eluf(s);
    }
    __syncthreads();   // BF
    if (t < 10){
        float s2 = fb2[t];
        const float* w2 = fw2 + (size_t)t * 128;
        for (int j = 0; j < 128; j++) s2 += h[j] * w2[j];
        lg[t] = s2;
    }
    __syncthreads();   // BG
    if (t == 0){
        float m = lg[0];
        for (int c = 1; c < 10; c++) m = fmaxf(m, lg[c]);
        float se = 0.f;
        for (int c = 0; c < 10; c++) se += expf(lg[c] - m);
        lse = m + logf(se);
    }
    __syncthreads();   // BH
    if (t < 10) out[(size_t)b*10 + t] = lg[t] - lse;
}

extern "C" void kernel_launch(void* const* d_in, const int* in_sizes, int n_in,
                              void* d_out, int out_size, void* d_ws, size_t ws_size,
                              hipStream_t stream) {
    const float* x   = (const float*)d_in[0];
    const float* pos = (const float*)d_in[1];
    const int*   src = (const int*)d_in[2];
    const int*   dst = (const int*)d_in[3];
    const float* W1  = (const float*)d_in[4];
    const float* r1  = (const float*)d_in[5];
    const float* b1  = (const float*)d_in[6];
    const float* W2  = (const float*)d_in[7];
    const float* r2  = (const float*)d_in[8];
    const float* b2  = (const float*)d_in[9];
    const float* W3  = (const float*)d_in[10];
    const float* r3  = (const float*)d_in[11];
    const float* b3  = (const float*)d_in[12];
    const float* fw1 = (const float*)d_in[13];
    const float* fb1 = (const float*)d_in[14];
    const float* fw2 = (const float*)d_in[15];
    const float* fb2 = (const float*)d_in[16];
    float* out = (float*)d_out;

    const int N   = in_sizes[0];
    const int E   = in_sizes[2];
    const int B   = N / NPG;
    const int EPG = E / B;
    const int S1  = B * 36;
    const int S2  = B * 25;

    float* w = (float*)d_ws;
    size_t off = 0;
    auto alloc = [&](size_t nelem){ size_t o = off; off += (nelem + 63) & ~(size_t)63; return o; };

    size_t o_scal = alloc(4);                 // amax0, amax1, amax2 bits
    size_t o_px1  = alloc((size_t)S1 * 32);
    size_t o_pp1  = alloc((size_t)S1 * 2);
    size_t o_sv1  = alloc(S1);
    size_t o_easrc= alloc(E);
    size_t o_ecart= alloc((size_t)2 * E);
    size_t o_kcnt = alloc(B);
    size_t o_rp2  = alloc((size_t)2 * S1);
    size_t o_rp3  = alloc((size_t)2 * S2);
    size_t o_px2  = alloc((size_t)S2 * 64);
    size_t o_pp2  = alloc((size_t)S2 * 2);
    size_t o_sv2  = alloc(S2);
    size_t o_wz2  = alloc((size_t)26 * 32 * 64 / 2 + 64);   // fp16 swizzled W2'
    size_t o_wz3  = alloc((size_t)26 * 64 * 64 / 2 + 64);   // fp16 swizzled W3'
    size_t o_accA = alloc(((size_t)S1 * 832 + 1) / 2 + 64); // fp16 A rows for conv2

    hipMemsetAsync(w + o_scal, 0, 4 * sizeof(float), stream);

    unsigned* scal = (unsigned*)(w + o_scal);
    _Float16* Wz2  = (_Float16*)(w + o_wz2);
    _Float16* Wz3  = (_Float16*)(w + o_wz3);
    _Float16* A16  = (_Float16*)(w + o_accA);

    // prep: W-swizzle + edge amax in one dispatch
    const int E4 = E / 4;
    int gA = (E4 + 255) / 256; if (gA > 512) gA = 512;
    const int nW = (26 * 32 * 64 + 26 * 64 * 64 + 255) / 256;   // 624
    prep_k<<<nW + gA, 256, 0, stream>>>(W2, r2, W3, r3, Wz2, Wz3, nW,
                                        pos, src, dst, E4, gA, scal + 0);

    // conv1 + pool1 + stage1->2 dedup/CSR, fully fused per graph
    conv1dedup_k<<<B, 512, 0, stream>>>(x, pos, src, dst, EPG, scal + 0, W1, r1, b1,
                                        w + o_px1, w + o_pp1, w + o_sv1,
                                        (int*)(w + o_easrc), (float2*)(w + o_ecart),
                                        (int*)(w + o_rp2), (int*)(w + o_kcnt), scal + 1);

    // conv2 phase A: gather (A16 to global; must precede mfma2pool which overwrites easrc/ecart)
    conv_gather32_k<<<S1 / 4, 256, 0, stream>>>(
        w + o_px1, (int*)(w + o_easrc), (const float2*)(w + o_ecart), scal + 1,
        (int*)(w + o_rp2), A16);

    // conv2 MFMA + pool2 + stage-2 -> stage-3 dedup/CSR, one block per graph (out2 never materializes)
    mfma2pool_k<<<B, 256, 0, stream>>>(
        A16, Wz2, b2,
        (int*)(w + o_easrc), (int*)(w + o_rp2), (int*)(w + o_kcnt),
        w + o_pp1, w + o_sv1, EPG,
        w + o_px2, w + o_pp2, w + o_sv2,
        (int*)(w + o_easrc), (float2*)(w + o_ecart),
        (int*)(w + o_rp3), (int*)(w + o_kcnt), scal + 2);

    // conv3 + final pool + MLP + log_softmax, one block per graph (out3 never leaves LDS)
    conv3pf_k<<<B, 1024, 0, stream>>>(
        w + o_px2,
        (int*)(w + o_easrc), (const float2*)(w + o_ecart), scal + 2,
        (int*)(w + o_rp3), Wz3, b3,
        w + o_pp2, w + o_sv2,
        fw1, fb1, fw2, fb2, out);
}

// Round 12
// 319.078 us; speedup vs baseline: 1.0944x; 1.0944x over previous
//
#include <hip/hip_runtime.h>
#include <math.h>

#define NPG 75
#define KDIM 5

typedef _Float16 half8 __attribute__((ext_vector_type(8)));
typedef float f32x4 __attribute__((ext_vector_type(4)));

__device__ __forceinline__ float eluf(float v){ return v > 0.f ? v : expf(v) - 1.f; }

__device__ __forceinline__ void atomAddF(float* p, float v){ unsafeAtomicAdd(p, v); }

__device__ __forceinline__ unsigned fenc(float f){
    unsigned u = __float_as_uint(f);
    return (u & 0x80000000u) ? ~u : (u | 0x80000000u);
}
__device__ __forceinline__ float fdec(unsigned u){
    return (u & 0x80000000u) ? __uint_as_float(u & 0x7FFFFFFFu) : __uint_as_float(~u);
}

// 25 accumulating FMAs with accumulators pinned to arch VGPRs ("v" constraint).
__device__ __forceinline__ void fma25(float (&r)[25], const float (&wx)[5], const float (&wyx)[5]){
    #pragma unroll
    for (int b1 = 0; b1 < 5; b1++)
        #pragma unroll
        for (int b0 = 0; b0 < 5; b0++)
            asm("v_fmac_f32 %0, %1, %2" : "+v"(r[b1 * 5 + b0]) : "v"(wx[b0]), "v"(wyx[b1]));
}

// spline basis: pseudo = cart/(2*amax)+0.5, clip[0,1], *4; 4 corner weights + kernel ids
__device__ __forceinline__ void spline2(float c0, float c1, float am, int* kks, float* wsp){
    float denom = 2.f * fmaxf(am, 1e-12f);
    float p0 = c0 / denom + 0.5f;
    float p1 = c1 / denom + 0.5f;
    p0 = fminf(fmaxf(p0, 0.f), 1.f) * 4.f;
    p1 = fminf(fmaxf(p1, 0.f), 1.f) * 4.f;
    float b0 = fminf(floorf(p0), 3.f);
    float b1 = fminf(floorf(p1), 3.f);
    float f0 = p0 - b0, f1 = p1 - b1;
    int i0 = (int)b0, i1 = (int)b1;
    wsp[0] = (1.f - f0) * (1.f - f1); kks[0] = i0     + KDIM *  i1;
    wsp[1] =        f0  * (1.f - f1); kks[1] = i0 + 1 + KDIM *  i1;
    wsp[2] = (1.f - f0) *        f1 ; kks[2] = i0     + KDIM * (i1 + 1);
    wsp[3] =        f0  *        f1 ; kks[3] = i0 + 1 + KDIM * (i1 + 1);
}

// per-lane spline payload write (identical arithmetic to the old espline_k)
__device__ __forceinline__ void spline_pay(float2 c, float denom, float* d){
    float p0 = fminf(fmaxf(c.x / denom + 0.5f, 0.f), 1.f) * 4.f;
    float p1 = fminf(fmaxf(c.y / denom + 0.5f, 0.f), 1.f) * 4.f;
    float b0 = fminf(floorf(p0), 3.f);
    float b1 = fminf(floorf(p1), 3.f);
    int i0 = (int)b0, i1 = (int)b1;
    float f0 = p0 - b0, f1 = p1 - b1;
    #pragma unroll
    for (int k = 0; k < 4; k++){
        d[k]     = (k == i0) ? (1.f - f0) : ((k == i0 + 1) ? f0 : 0.f);
        d[4 + k] = (k == i1) ? (1.f - f1) : ((k == i1 + 1) ? f1 : 0.f);
    }
}

// ---------------- prep: W-swizzle (blocks [0,nW)) + edge amax (blocks [nW,nW+gA)) in ONE dispatch ----------------
__global__ __launch_bounds__(256) void prep_k(
        const float* __restrict__ W2, const float* __restrict__ r2,
        const float* __restrict__ W3, const float* __restrict__ r3,
        _Float16* __restrict__ Wz2, _Float16* __restrict__ Wz3, int nW,
        const float* __restrict__ pos, const int* __restrict__ src,
        const int* __restrict__ dst, int E4, int gA, unsigned* __restrict__ outbits){
    const int blk = blockIdx.x;
    if (blk < nW){
        int gid = blk * 256 + threadIdx.x;
        const int T2 = 26 * 32 * 64;
        const int T3 = 26 * 64 * 64;
        const float* W; const float* root; _Float16* Wz; int FIN; int g;
        if (gid < T2){ W = W2; root = r2; Wz = Wz2; FIN = 32; g = gid; }
        else if (gid < T2 + T3){ W = W3; root = r3; Wz = Wz3; FIN = 64; g = gid - T2; }
        else return;
        int k = g >> 6, n = g & 63;
        float v = (k < 25 * FIN) ? W[(size_t)k * 64 + n] : root[(size_t)(k - 25 * FIN) * 64 + n];
        int kt = k >> 5, kr = k & 31, quad = kr >> 3, j = kr & 7;
        int lane = (quad << 4) | (n & 15);
        int nt = n >> 4;
        Wz[(((size_t)(kt * 4 + nt) * 64 + lane) << 3) + j] = (_Float16)v;
    } else {
        float cand = 0.f;
        for (int i = (blk - nW) * 256 + threadIdx.x; i < E4; i += gA * 256){
            int4 s4 = ((const int4*)src)[i];
            int4 d4 = ((const int4*)dst)[i];
            #pragma unroll
            for (int k = 0; k < 4; k++){
                int s = (&s4.x)[k], d = (&d4.x)[k];
                float c0 = pos[s*2]   - pos[d*2];
                float c1 = pos[s*2+1] - pos[d*2+1];
                cand = fmaxf(cand, fmaxf(fabsf(c0), fabsf(c1)));
            }
        }
        __shared__ float sm[256];
        sm[threadIdx.x] = cand; __syncthreads();
        for (int o = 128; o > 0; o >>= 1){
            if (threadIdx.x < o) sm[threadIdx.x] = fmaxf(sm[threadIdx.x], sm[threadIdx.x + o]);
            __syncthreads();
        }
        if (threadIdx.x == 0) atomicMax(outbits, __float_as_uint(sm[0]));
    }
}

// ---------------- conv1 (Fin=1->32) + pool1 + stage1->2 dedup/CSR, fully fused, 1 block/graph ----------------
__global__ __launch_bounds__(512) void conv1dedup_k(
        const float* __restrict__ x, const float* __restrict__ pos,
        const int* __restrict__ src, const int* __restrict__ dst, int EPG,
        const unsigned* __restrict__ amaxp,
        const float* __restrict__ W1, const float* __restrict__ r1, const float* __restrict__ b1,
        float* __restrict__ px1, float* __restrict__ pp1, float* __restrict__ sv1,
        int* __restrict__ easrc, float2* __restrict__ ecart,
        int* __restrict__ rowptr2, int* __restrict__ kcnt, unsigned* __restrict__ amaxbits){
    __shared__ __align__(16) float acc[NPG * 28];
    __shared__ float deg[NPG];
    __shared__ float xl[NPG], p0l[NPG], p1l[NPG];
    __shared__ int   cli[NPG];
    __shared__ float W1s[800], r1s[32], b1s[32];
    __shared__ unsigned px[36 * 32];
    __shared__ float cnt[36], ps[72], ppS[72];
    __shared__ unsigned pm[36 * 36];
    __shared__ float degs[36];
    __shared__ int rs[37], cur[36];
    __shared__ float red[8];
    __shared__ unsigned short sdS[2048];   // packed (s | d<<8) per edge

    const int b = blockIdx.x, t = threadIdx.x;
    const int lane = t & 63, wid = t >> 6;
    const int n0 = b * NPG, e0 = b * EPG;

    const float am = __uint_as_float(*amaxp);

    for (int i = t; i < NPG * 28; i += 512) acc[i] = 0.f;
    for (int i = t; i < 36 * 32; i += 512) px[i] = 0u;
    for (int i = t; i < 36 * 36; i += 512) pm[i] = 0xFFFFFFFFu;
    if (t < NPG) deg[t] = 0.f;
    if (t < 36){ cnt[t] = 0.f; degs[t] = 0.f; }
    if (t < 72) ps[t] = 0.f;
    for (int i = t; i < 800; i += 512) W1s[i] = W1[i];
    if (t < 32){ r1s[t] = r1[t]; b1s[t] = b1[t]; }
    if (t < NPG){
        float p0 = pos[(n0 + t) * 2], p1 = pos[(n0 + t) * 2 + 1];
        xl[t] = x[n0 + t]; p0l[t] = p0; p1l[t] = p1;
        int c0 = min(max((int)floorf(p0 / 5.f), 0), 5);
        int c1 = min(max((int)floorf(p1 / 5.f), 0), 5);
        cli[t] = c1 * 6 + c0;
    }
    __syncthreads();   // B1

    if (t < NPG){
        int c = cli[t];
        atomAddF(&cnt[c], 1.f);
        atomAddF(&ps[c*2],     p0l[t]);
        atomAddF(&ps[c*2 + 1], p1l[t]);
    }
    #pragma unroll 4
    for (int it = 0; it < 4; it++){
        int e = t + it * 512;
        if (e < EPG){
            int s = src[e0 + e] - n0;
            int d = dst[e0 + e] - n0;
            sdS[e] = (unsigned short)(s | (d << 8));
            float c0 = p0l[s] - p0l[d];
            float c1 = p1l[s] - p1l[d];
            int kks[4]; float wsp[4];
            spline2(c0, c1, am, kks, wsp);
            float xv = xl[s];
            #pragma unroll
            for (int c = 0; c < 4; c++) atomAddF(&acc[d*28 + kks[c]], wsp[c] * xv);
            atomAddF(&deg[d], 1.f);
        }
    }
    __syncthreads();   // B2

    if (t < 36){
        float c = cnt[t], m = fmaxf(c, 1.f);
        float q0 = ps[t*2] / m, q1 = ps[t*2 + 1] / m;
        ppS[t*2] = q0; ppS[t*2 + 1] = q1;
        pp1[(b*36 + t)*2]     = q0;
        pp1[(b*36 + t)*2 + 1] = q1;
        sv1[b*36 + t] = (c > 0.f) ? 1.f : 0.f;
    }
    {
        const int o = t & 31;
        float wreg[25];
        #pragma unroll
        for (int k = 0; k < 25; k++) wreg[k] = W1s[k * 32 + o];
        const float rro = r1s[o], bbo = b1s[o];
        const int ii = t >> 5;
        #pragma unroll
        for (int r = 0; r < 5; r++){
            int i = ii + r * 16;
            if (i < NPG){
                const float4* ar = (const float4*)(acc + i * 28);
                float s = 0.f;
                #pragma unroll
                for (int q = 0; q < 7; q++){
                    float4 aq = ar[q];
                    s += aq.x * wreg[q*4];
                    if (q*4 + 1 < 25) s += aq.y * wreg[q*4 + 1];
                    if (q*4 + 2 < 25) s += aq.z * wreg[q*4 + 2];
                    if (q*4 + 3 < 25) s += aq.w * wreg[q*4 + 3];
                }
                float v = s / fmaxf(deg[i], 1.f) + xl[i] * rro + bbo;
                v = eluf(v);
                atomicMax(&px[cli[i]*32 + o], fenc(v));
            }
        }
    }
    int lab[4];
    #pragma unroll 4
    for (int it = 0; it < 4; it++){
        int e = t + it * 512;
        lab[it] = 0;
        if (e < EPG){
            int sd = (int)sdS[e];
            int a  = cli[sd & 255];
            int bb = cli[sd >> 8];
            lab[it] = a | (bb << 8) | ((a != bb) ? 0x10000 : 0);
            if (a != bb) atomicMin(&pm[a * 36 + bb], (unsigned)e);
        }
    }
    __syncthreads();   // B3

    for (int idx = t; idx < 36 * 32; idx += 512){
        int s_ = idx >> 5;
        px1[(size_t)(b*36)*32 + idx] = (cnt[s_] > 0.f) ? fdec(px[idx]) : 0.f;
    }
    float cand = 0.f;
    unsigned keptM = 0;
    #pragma unroll 4
    for (int it = 0; it < 4; it++){
        int e = t + it * 512;
        int L = lab[it];
        if (L & 0x10000){
            int a = L & 255, bb = (L >> 8) & 255;
            if (pm[a * 36 + bb] == (unsigned)e){
                keptM |= 1u << it;
                atomAddF(&degs[bb], 1.f);
                float c0 = ppS[a*2]     - ppS[bb*2];
                float c1 = ppS[a*2 + 1] - ppS[bb*2 + 1];
                cand = fmaxf(cand, fmaxf(fabsf(c0), fabsf(c1)));
            }
        }
    }
    #pragma unroll
    for (int o = 1; o < 64; o <<= 1) cand = fmaxf(cand, __shfl_xor(cand, o, 64));
    if (lane == 0) red[wid] = cand;
    __syncthreads();   // B4
    if (t == 0){
        float m = red[0];
        #pragma unroll
        for (int i = 1; i < 8; i++) m = fmaxf(m, red[i]);
        atomicMax(amaxbits, __float_as_uint(m));
    }
    if (t < 64){
        int v = (t < 36) ? (int)degs[t] : 0;
        int incl = v;
        #pragma unroll
        for (int o = 1; o < 64; o <<= 1){
            int u = __shfl_up(incl, o, 64);
            if (t >= o) incl += u;
        }
        if (t == 0) rs[0] = 0;
        if (t < 36) rs[t + 1] = incl;
    }
    __syncthreads();   // B5
    if (t < 36){
        rowptr2[(b*36 + t)*2]     = e0 + rs[t];
        rowptr2[(b*36 + t)*2 + 1] = e0 + rs[t + 1];
        cur[t] = rs[t];
    }
    if (t == 0) kcnt[b] = rs[36];
    __syncthreads();   // B6
    #pragma unroll 4
    for (int it = 0; it < 4; it++){
        if (keptM & (1u << it)){
            int L = lab[it];
            int a = L & 255, bb = (L >> 8) & 255;
            int slot = atomicAdd(&cur[bb], 1);
            easrc[e0 + slot] = b*36 + a;
            ecart[e0 + slot] = make_float2(ppS[a*2] - ppS[bb*2], ppS[a*2 + 1] - ppS[bb*2 + 1]);
        }
    }
}

// ---------------- stage2->3: pool (size=7,G=5) + dedup + CSR from stage-2 CSR — ROUND-8 VERIFIED ----------------
__global__ __launch_bounds__(1024) void dedup_pool_k(
        const int* __restrict__ easrc_in, const int* __restrict__ rowptr_in,
        const int* __restrict__ kcnt_in,
        const float* __restrict__ xin,                                    // out2 [S1][64]
        const float* __restrict__ pp1, const float* __restrict__ sv1,
        int EPG,
        float* __restrict__ px2, float* __restrict__ pp2, float* __restrict__ sv2,
        int* __restrict__ easrc, float2* __restrict__ ecart,
        int* __restrict__ rowptr2, int* __restrict__ kcnt, unsigned* __restrict__ amaxbits){
    constexpr int GG = 25, NN = 36;
    __shared__ unsigned pm[GG * GG];
    __shared__ float degs[GG];
    __shared__ int rs[GG + 1];
    __shared__ int cur[GG];
    __shared__ float red[16];
    __shared__ int   clS[NN];
    __shared__ int   vld[NN];
    __shared__ int   rsS[NN + 1];
    __shared__ float ppS[2 * GG];
    __shared__ unsigned px[GG * 64];
    __shared__ float cnt[GG], ps[2 * GG];
    __shared__ unsigned short abS[1280];   // packed (a2 | b2<<8 | valid<<15) per kept slot

    const int b = blockIdx.x, t = threadIdx.x;
    const int lane = t & 63, wid = t >> 6;
    const int e0 = b * EPG;
    const int cb25 = b * GG;
    const int nb36 = b * NN;

    for (int i = t; i < GG * GG; i += 1024) pm[i] = 0xFFFFFFFFu;
    for (int i = t; i < GG * 64; i += 1024) px[i] = 0u;
    if (t < GG){ degs[t] = 0.f; cnt[t] = 0.f; }
    if (t < 2 * GG) ps[t] = 0.f;
    if (t < NN){
        float v  = sv1[nb36 + t];
        float p0 = pp1[(nb36 + t)*2], p1 = pp1[(nb36 + t)*2 + 1];
        int c0 = min(max((int)floorf(p0 / 7.f), 0), 4);
        int c1 = min(max((int)floorf(p1 / 7.f), 0), 4);
        clS[t] = c1 * 5 + c0;
        vld[t] = (v > 0.f) ? 1 : 0;
        rsS[t] = rowptr_in[(nb36 + t)*2] - e0;
    }
    if (t == 0) rsS[NN] = kcnt_in[b];
    __syncthreads();

    const int kn = rsS[NN];

    if (t < NN && vld[t]){
        int c = clS[t];
        atomAddF(&cnt[c], 1.f);
        atomAddF(&ps[c*2],     pp1[(nb36 + t)*2]);
        atomAddF(&ps[c*2 + 1], pp1[(nb36 + t)*2 + 1]);
    }
    for (int idx = t; idx < NN * 64; idx += 1024){
        int i = idx >> 6, f = idx & 63;
        if (vld[i])
            atomicMax(&px[clS[i]*64 + f], fenc(xin[(size_t)(nb36 + i)*64 + f]));
    }
    #pragma unroll 2
    for (int it = 0; it < 2; it++){
        int s = t + it * 1024;
        if (s < kn){
            int r = 0;
            while (r < NN - 1 && rsS[r + 1] <= s) r++;   // dst row of this slot
            int a2 = clS[easrc_in[e0 + s] - nb36];
            int b2 = clS[r];
            abS[s] = (unsigned short)(a2 | (b2 << 8) | ((a2 != b2) ? 0x8000 : 0));
            if (a2 != b2) atomicMin(&pm[a2 * GG + b2], (unsigned)s);
        }
    }
    __syncthreads();

    if (t < GG){
        float c = cnt[t], m = fmaxf(c, 1.f);
        float q0 = ps[t*2] / m, q1 = ps[t*2 + 1] / m;
        ppS[t*2] = q0; ppS[t*2 + 1] = q1;
        pp2[(cb25 + t)*2]     = q0;
        pp2[(cb25 + t)*2 + 1] = q1;
        sv2[cb25 + t] = (c > 0.f) ? 1.f : 0.f;
    }
    for (int idx = t; idx < GG * 64; idx += 1024){
        int s_ = idx >> 6;
        px2[(size_t)cb25*64 + idx] = (cnt[s_] > 0.f) ? fdec(px[idx]) : 0.f;
    }
    __syncthreads();

    float cand = 0.f;
    #pragma unroll 2
    for (int it = 0; it < 2; it++){
        int s = t + it * 1024;
        if (s < kn){
            int A = (int)abS[s];
            if (A & 0x8000){
                int a2 = A & 255, b2 = (A >> 8) & 127;
                if (pm[a2 * GG + b2] == (unsigned)s){
                    atomAddF(&degs[b2], 1.f);
                    float c0 = ppS[a2*2]     - ppS[b2*2];
                    float c1 = ppS[a2*2 + 1] - ppS[b2*2 + 1];
                    cand = fmaxf(cand, fmaxf(fabsf(c0), fabsf(c1)));
                }
            }
        }
    }
    #pragma unroll
    for (int o = 1; o < 64; o <<= 1) cand = fmaxf(cand, __shfl_xor(cand, o, 64));
    if (lane == 0) red[wid] = cand;
    __syncthreads();
    if (t == 0){
        float m = red[0];
        #pragma unroll
        for (int i = 1; i < 16; i++) m = fmaxf(m, red[i]);
        atomicMax(amaxbits, __float_as_uint(m));
    }
    if (t < 64){
        int v = (t < GG) ? (int)degs[t] : 0;
        int incl = v;
        #pragma unroll
        for (int o = 1; o < 64; o <<= 1){
            int u = __shfl_up(incl, o, 64);
            if (t >= o) incl += u;
        }
        if (t == 0) rs[0] = 0;
        if (t < GG) rs[t + 1] = incl;
    }
    __syncthreads();
    if (t < GG){
        rowptr2[(cb25 + t)*2]     = e0 + rs[t];
        rowptr2[(cb25 + t)*2 + 1] = e0 + rs[t + 1];
        cur[t] = rs[t];
    }
    if (t == 0) kcnt[b] = rs[GG];
    __syncthreads();
    #pragma unroll 2
    for (int it = 0; it < 2; it++){
        int s = t + it * 1024;
        if (s < kn){
            int A = (int)abS[s];
            if (A & 0x8000){
                int a2 = A & 255, b2 = (A >> 8) & 127;
                if (pm[a2 * GG + b2] == (unsigned)s){
                    int slot = atomicAdd(&cur[b2], 1);
                    easrc[e0 + slot] = cb25 + a2;
                    ecart[e0 + slot] = make_float2(ppS[a2*2] - ppS[b2*2], ppS[a2*2 + 1] - ppS[b2*2 + 1]);
                }
            }
        }
    }
}

// ---------------- conv2 phase A: gather with wave-parallel inline spline (round-6 verified) ----------------
__global__ __launch_bounds__(256) void conv_gather32_k(
        const float* __restrict__ x, const int* __restrict__ easrc,
        const float2* __restrict__ ecart, const unsigned* __restrict__ amaxp,
        const int* __restrict__ rowptr2, _Float16* __restrict__ Aout){
    constexpr int FIN = 32;
    constexpr int KTOT = 26 * FIN;
    __shared__ __align__(16) float pay[4][36][8];
    __shared__ int asrcS[4][36];
    const int w = threadIdx.x >> 6, lane = threadIdx.x & 63;
    const int node = blockIdx.x * 4 + w;
    const int row0 = rowptr2[node*2], row1 = rowptr2[node*2 + 1];
    const int ne = row1 - row0;
    const int sub = lane >> 5;
    const int f = lane & (FIN - 1);

    if (lane < ne){
        float am = __uint_as_float(*amaxp);
        spline_pay(ecart[row0 + lane], 2.f * fmaxf(am, 1e-12f), &pay[w][lane][0]);
        asrcS[w][lane] = easrc[row0 + lane];
    }
    // wave-coherent LDS: no barrier needed

    float r[25];
    #pragma unroll
    for (int b = 0; b < 25; b++) r[b] = 0.f;

    int j = sub;
    int aNext = 0;
    float xvCur = 0.f;
    if (j < ne){
        int aCur = asrcS[w][j];
        xvCur = x[(size_t)aCur * FIN + f];
        int j1 = (j + 2 < ne) ? j + 2 : j;
        aNext = asrcS[w][j1];
    }
    for (; j < ne; j += 2){
        int jN  = j + 2;
        int jNs = (jN < ne) ? jN : j;
        int jN2 = (jN + 2 < ne) ? jN + 2 : jNs;
        float xvN = x[(size_t)aNext * FIN + f];   // aNext resolved last iteration
        int aN2 = asrcS[w][jN2];
        float4 wa = *(const float4*)&pay[w][j][0];
        float4 wb = *(const float4*)&pay[w][j][4];
        float wx4 = 1.f - (wa.x + wa.y + wa.z + wa.w);
        float wy4 = 1.f - (wb.x + wb.y + wb.z + wb.w);
        float wx[5]  = {wa.x, wa.y, wa.z, wa.w, wx4};
        float wyx[5] = {wb.x * xvCur, wb.y * xvCur, wb.z * xvCur, wb.w * xvCur, wy4 * xvCur};
        fma25(r, wx, wyx);
        xvCur = xvN; aNext = aN2;
    }

    #pragma unroll
    for (int b = 0; b < 25; b++) r[b] += __shfl_xor(r[b], 32, 64);

    float inv = 1.f / (float)max(ne, 1);
    _Float16* dstrow = Aout + (size_t)node * KTOT;
    #pragma unroll
    for (int b = 0; b < 25; b++)
        if ((b & 1) == sub) dstrow[b * 32 + f] = (_Float16)(r[b] * inv);
    if (sub == 0) dstrow[25 * 32 + f] = (_Float16)x[(size_t)node * 32 + f];
}

// ---------------- conv2 phase B: MFMA GEMM, full K, fused bias+ELU epilogue (round-6 verified) ----------------
__global__ __launch_bounds__(256) void conv_mfma832_k(
        const _Float16* __restrict__ A, const _Float16* __restrict__ Wz,
        const float* __restrict__ bias, int M, float* __restrict__ out){
    constexpr int KTOT = 832;
    constexpr int NSTEP = KTOT / 32;
    const int w = threadIdx.x >> 6, lane = threadIdx.x & 63;
    const int m0 = blockIdx.x * 64 + w * 16;
    const int quad = lane >> 4;

    f32x4 acc[4];
    #pragma unroll
    for (int nt = 0; nt < 4; nt++) acc[nt] = (f32x4){0.f, 0.f, 0.f, 0.f};

    const half8* __restrict__ Arow = (const half8*)(A + (size_t)(m0 + (lane & 15)) * KTOT);
    const half8* __restrict__ Wp   = (const half8*)Wz + lane;

    for (int kt = 0; kt < NSTEP; kt++){
        half8 a = Arow[kt * 4 + quad];
        #pragma unroll
        for (int nt = 0; nt < 4; nt++){
            half8 b = Wp[(kt * 4 + nt) * 64];
            acc[nt] = __builtin_amdgcn_mfma_f32_16x16x32_f16(a, b, acc[nt], 0, 0, 0);
        }
    }

    float* cp = out + (size_t)m0 * 64;
    const int r = quad * 4, c = lane & 15;
    #pragma unroll
    for (int nt = 0; nt < 4; nt++){
        float bv = bias[nt * 16 + c];
        #pragma unroll
        for (int i = 0; i < 4; i++)
            cp[(size_t)(r + i) * 64 + nt * 16 + c] = eluf(acc[nt][i] + bv);
    }
}

// ---------------- conv3pf: per-graph conv3 (gather from global px2 + MFMA K-split) + final pool + MLP ----------------
// (round-10 verified, unchanged)
__global__ __launch_bounds__(1024) void conv3pf_k(
        const float* __restrict__ x,                                     // px2 [S2][64]
        const int* __restrict__ easrc, const float2* __restrict__ ecart,
        const unsigned* __restrict__ amaxp,
        const int* __restrict__ rowptr3,
        const _Float16* __restrict__ Wz, const float* __restrict__ bias,
        const float* __restrict__ pp2, const float* __restrict__ sv2,
        const float* __restrict__ fw1, const float* __restrict__ fb1,
        const float* __restrict__ fw2, const float* __restrict__ fb2,
        float* __restrict__ out){
    constexpr int PAD = 1672;  // 1664 + 8
    __shared__ __align__(16) _Float16 Alds[32 * PAD];     // 107,008 B
    // scr phase A: pay[16][24][8] = [0,3072) ; phase B: Cpart [0,2048) | out3L [2048,4096)
    __shared__ __align__(16) float scr[4096];
    __shared__ int asrcS[16][24];
    __shared__ unsigned px4[4 * 64];
    __shared__ float cnt4[4];
    __shared__ int cli25[25];
    __shared__ float xr[256];
    __shared__ float h[128];
    __shared__ float lg[10];
    __shared__ float lse;

    const int b = blockIdx.x, t = threadIdx.x;
    const int w = t >> 6, lane = t & 63;
    const int cb25 = b * 25;

    // init: zero A-tile rows 25..31; px4/cnt4; final-pool cluster ids from pp2/sv2
    {
        unsigned* az = (unsigned*)&Alds[25 * PAD];
        for (int i = t; i < 7 * PAD / 2; i += 1024) az[i] = 0u;
    }
    if (t < 256) px4[t] = 0u;
    if (t < 4) cnt4[t] = 0.f;
    if (t < 25){
        float v = sv2[cb25 + t];
        float p0 = pp2[(cb25 + t)*2], p1 = pp2[(cb25 + t)*2 + 1];
        int c0 = min(max((int)floorf(p0 / 14.f), 0), 1);
        int c1 = min(max((int)floorf(p1 / 14.f), 0), 1);
        cli25[t] = (v > 0.f) ? (c1 * 2 + c0) : -1;
    }

    // gather (conv3f verbatim; x = px2 global, node = cb25 + nloc, guard nloc < 25)
    const float am = __uint_as_float(*amaxp);
    const float denom = 2.f * fmaxf(am, 1e-12f);
    float* payW = scr + w * 192;

    #pragma unroll
    for (int i = 0; i < 2; i++){
        const int nloc = w * 2 + i;
        if (nloc < 25){
            const int node = cb25 + nloc;
            const int row0 = rowptr3[node*2], row1 = rowptr3[node*2 + 1];
            const int ne = row1 - row0;   // <= 24

            if (lane < ne){
                spline_pay(ecart[row0 + lane], denom, payW + lane * 8);
                asrcS[w][lane] = easrc[row0 + lane];   // global stage-3 cluster id
            }
            // wave-coherent LDS: no barrier needed

            float r[25];
            #pragma unroll
            for (int bq = 0; bq < 25; bq++) r[bq] = 0.f;

            int j = 0;
            int aNext = 0;
            float xvCur = 0.f;
            if (j < ne){
                int aCur = asrcS[w][j];
                xvCur = x[(size_t)aCur * 64 + lane];
                int j1 = (1 < ne) ? 1 : 0;
                aNext = asrcS[w][j1];
            }
            for (; j < ne; j++){
                int jN  = j + 1;
                int jNs = (jN < ne) ? jN : j;
                int jN2 = (jN + 1 < ne) ? jN + 1 : jNs;
                float xvN = x[(size_t)aNext * 64 + lane];
                int aN2 = asrcS[w][jN2];
                float4 wa = *(const float4*)(payW + j * 8);
                float4 wb = *(const float4*)(payW + j * 8 + 4);
                float wx4 = 1.f - (wa.x + wa.y + wa.z + wa.w);
                float wy4 = 1.f - (wb.x + wb.y + wb.z + wb.w);
                float wx[5]  = {wa.x, wa.y, wa.z, wa.w, wx4};
                float wyx[5] = {wb.x * xvCur, wb.y * xvCur, wb.z * xvCur, wb.w * xvCur, wy4 * xvCur};
                fma25(r, wx, wyx);
                xvCur = xvN; aNext = aN2;
            }

            float inv = 1.f / (float)max(ne, 1);
            _Float16* dstrow = &Alds[nloc * PAD];
            #pragma unroll
            for (int bq = 0; bq < 25; bq++) dstrow[bq * 64 + lane] = (_Float16)(r[bq] * inv);
            dstrow[25 * 64 + lane] = (_Float16)x[(size_t)node * 64 + lane];
        }
    }
    __syncthreads();   // BA — gather + zero-fill complete; pay region dead

    if (t < 25 && cli25[t] >= 0) atomAddF(&cnt4[cli25[t]], 1.f);

    float* Cpart = scr;            // [8][256]
    float* out3L = scr + 2048;     // [32][64]

    // MFMA (conv3f verbatim): 8 tiles (mt 0..1, nt 0..3) x K-split 2
    const int tile = w & 7, khalf = w >> 3;
    const int mt = tile >> 2, nt = tile & 3;
    const int quad = lane >> 4, mr = lane & 15;
    f32x4 acc = (f32x4){0.f, 0.f, 0.f, 0.f};
    const _Float16* arow = &Alds[(mt * 16 + mr) * PAD];
    const half8* __restrict__ Wp = (const half8*)Wz + lane;
    const int kt0 = khalf * 26;
    for (int kt = 0; kt < 26; kt++){
        half8 a = *(const half8*)(arow + (kt0 + kt) * 32 + quad * 8);
        half8 bb = Wp[((kt0 + kt) * 4 + nt) * 64];
        acc = __builtin_amdgcn_mfma_f32_16x16x32_f16(a, bb, acc, 0, 0, 0);
    }
    const int r_ = quad * 4, c_ = lane & 15;
    if (khalf == 1){
        float* Cp = Cpart + tile * 256;
        #pragma unroll
        for (int i = 0; i < 4; i++) Cp[(r_ + i) * 16 + c_] = acc[i];
    }
    __syncthreads();   // BB
    if (khalf == 0){
        const float* Cp = Cpart + tile * 256;
        float bv = bias[nt * 16 + c_];
        #pragma unroll
        for (int i = 0; i < 4; i++)
            out3L[(mt * 16 + r_ + i) * 64 + nt * 16 + c_] = eluf(acc[i] + Cp[(r_ + i) * 16 + c_] + bv);
    }
    __syncthreads();   // BC — out3 rows 0..24 valid in LDS

    // final pool (2x2) + MLP + log_softmax (final_k verbatim, xin = out3L)
    for (int idx = t; idx < 25 * 64; idx += 1024){
        int i = idx >> 6, f = idx & 63;
        if (cli25[i] >= 0)
            atomicMax(&px4[cli25[i]*64 + f], fenc(out3L[i * 64 + f]));
    }
    __syncthreads();   // BD
    if (t < 256) xr[t] = (cnt4[t >> 6] > 0.f) ? fdec(px4[t]) : 0.f;
    __syncthreads();   // BE
    if (t < 128){
        float s = fb1[t];
        const float4* wrow = (const float4*)(fw1 + (size_t)t * 256);
        #pragma unroll 4
        for (int i = 0; i < 64; i++){
            float4 q = wrow[i];
            s += xr[i*4]   * q.x;
            s += xr[i*4+1] * q.y;
            s += xr[i*4+2] * q.z;
            s += xr[i*4+3] * q.w;
        }
        h[t] = eluf(s);
    }
    __syncthreads();   // BF
    if (t < 10){
        float s2 = fb2[t];
        const float* w2 = fw2 + (size_t)t * 128;
        for (int j = 0; j < 128; j++) s2 += h[j] * w2[j];
        lg[t] = s2;
    }
    __syncthreads();   // BG
    if (t == 0){
        float m = lg[0];
        for (int c = 1; c < 10; c++) m = fmaxf(m, lg[c]);
        float se = 0.f;
        for (int c = 0; c < 10; c++) se += expf(lg[c] - m);
        lse = m + logf(se);
    }
    __syncthreads();   // BH
    if (t < 10) out[(size_t)b*10 + t] = lg[t] - lse;
}

extern "C" void kernel_launch(void* const* d_in, const int* in_sizes, int n_in,
                              void* d_out, int out_size, void* d_ws, size_t ws_size,
                              hipStream_t stream) {
    const float* x   = (const float*)d_in[0];
    const float* pos = (const float*)d_in[1];
    const int*   src = (const int*)d_in[2];
    const int*   dst = (const int*)d_in[3];
    const float* W1  = (const float*)d_in[4];
    const float* r1  = (const float*)d_in[5];
    const float* b1  = (const float*)d_in[6];
    const float* W2  = (const float*)d_in[7];
    const float* r2  = (const float*)d_in[8];
    const float* b2  = (const float*)d_in[9];
    const float* W3  = (const float*)d_in[10];
    const float* r3  = (const float*)d_in[11];
    const float* b3  = (const float*)d_in[12];
    const float* fw1 = (const float*)d_in[13];
    const float* fb1 = (const float*)d_in[14];
    const float* fw2 = (const float*)d_in[15];
    const float* fb2 = (const float*)d_in[16];
    float* out = (float*)d_out;

    const int N   = in_sizes[0];
    const int E   = in_sizes[2];
    const int B   = N / NPG;
    const int EPG = E / B;
    const int S1  = B * 36;
    const int S2  = B * 25;

    float* w = (float*)d_ws;
    size_t off = 0;
    auto alloc = [&](size_t nelem){ size_t o = off; off += (nelem + 63) & ~(size_t)63; return o; };

    size_t o_scal = alloc(4);                 // amax0, amax1, amax2 bits
    size_t o_px1  = alloc((size_t)S1 * 32);
    size_t o_pp1  = alloc((size_t)S1 * 2);
    size_t o_sv1  = alloc(S1);
    size_t o_easrc= alloc(E);
    size_t o_ecart= alloc((size_t)2 * E);
    size_t o_kcnt = alloc(B);
    size_t o_rp2  = alloc((size_t)2 * S1);
    size_t o_rp3  = alloc((size_t)2 * S2);
    size_t o_out2 = alloc((size_t)S1 * 64);
    size_t o_px2  = alloc((size_t)S2 * 64);
    size_t o_pp2  = alloc((size_t)S2 * 2);
    size_t o_sv2  = alloc(S2);
    size_t o_wz2  = alloc((size_t)26 * 32 * 64 / 2 + 64);   // fp16 swizzled W2'
    size_t o_wz3  = alloc((size_t)26 * 64 * 64 / 2 + 64);   // fp16 swizzled W3'
    size_t o_accA = alloc(((size_t)S1 * 832 + 1) / 2);      // fp16 A rows for conv2 only

    hipMemsetAsync(w + o_scal, 0, 4 * sizeof(float), stream);

    unsigned* scal = (unsigned*)(w + o_scal);
    _Float16* Wz2  = (_Float16*)(w + o_wz2);
    _Float16* Wz3  = (_Float16*)(w + o_wz3);
    _Float16* A16  = (_Float16*)(w + o_accA);

    // prep: W-swizzle + edge amax in one dispatch
    const int E4 = E / 4;
    int gA = (E4 + 255) / 256; if (gA > 512) gA = 512;
    const int nW = (26 * 32 * 64 + 26 * 64 * 64 + 255) / 256;   // 624
    prep_k<<<nW + gA, 256, 0, stream>>>(W2, r2, W3, r3, Wz2, Wz3, nW,
                                        pos, src, dst, E4, gA, scal + 0);

    // conv1 + pool1 + stage1->2 dedup/CSR, fully fused per graph
    conv1dedup_k<<<B, 512, 0, stream>>>(x, pos, src, dst, EPG, scal + 0, W1, r1, b1,
                                        w + o_px1, w + o_pp1, w + o_sv1,
                                        (int*)(w + o_easrc), (float2*)(w + o_ecart),
                                        (int*)(w + o_rp2), (int*)(w + o_kcnt), scal + 1);

    // conv2 (Fin=32 -> 64): separated gather + MFMA (must precede dedup_pool: easrc/ecart in-place reuse)
    conv_gather32_k<<<S1 / 4, 256, 0, stream>>>(
        w + o_px1, (int*)(w + o_easrc), (const float2*)(w + o_ecart), scal + 1,
        (int*)(w + o_rp2), A16);
    conv_mfma832_k<<<S1 / 64, 256, 0, stream>>>(A16, Wz2, b2, S1, w + o_out2);

    // pool2 + stage-2 -> stage-3 dedup + CSR (round-8 verified, px2 to HBM)
    dedup_pool_k<<<B, 1024, 0, stream>>>(
        (int*)(w + o_easrc), (int*)(w + o_rp2), (int*)(w + o_kcnt),
        w + o_out2, w + o_pp1, w + o_sv1, EPG,
        w + o_px2, w + o_pp2, w + o_sv2,
        (int*)(w + o_easrc), (float2*)(w + o_ecart),
        (int*)(w + o_rp3), (int*)(w + o_kcnt), scal + 2);

    // conv3 + final pool + MLP + log_softmax, one block per graph (out3 never leaves LDS)
    conv3pf_k<<<B, 1024, 0, stream>>>(
        w + o_px2,
        (int*)(w + o_easrc), (const float2*)(w + o_ecart), scal + 2,
        (int*)(w + o_rp3), Wz3, b3,
        w + o_pp2, w + o_sv2,
        fw1, fb1, fw2, fb2, out);
}